// Round 10
// baseline (797.294 us; speedup 1.0000x reference)
//
#include <hip/hip_runtime.h>

#define IN_F   8192
#define OUT_F  14336
#define M_TOK  64
#define KPI    4096               // int32 per weight row
#define NBLK   112                // n-blocks (128 n each)
#define KSPLIT 4
#define PSTR   (M_TOK * OUT_F)    // floats per k-partial
#define NREP   4                  // instrumentation: repeat K-loop (epilogue /4)

typedef __attribute__((ext_vector_type(8))) short          bf16x8;
typedef __attribute__((ext_vector_type(8))) unsigned short u16x8;
typedef __attribute__((ext_vector_type(4))) float          f32x4;

__device__ __forceinline__ unsigned short f2bf_rne(float f) {
    unsigned u = __builtin_bit_cast(unsigned, f);
    u += 0x7FFFu + ((u >> 16) & 1u);
    return (unsigned short)(u >> 16);
}

// x fp32 -> A-fragment-swizzled bf16 (R6-R9-verified): 16-B unit (F, mt, lane)
// holds x[m = mt*16 + (lane&15)][k = F*32 + (lane>>4)*8 + j].
__global__ __launch_bounds__(256) void qlin_prep(const float* __restrict__ x,
                                                 unsigned short* __restrict__ xs) {
    int tid  = blockIdx.x * 256 + threadIdx.x;      // 65536
    int lane = tid & 63;
    int mt   = (tid >> 6) & 3;
    int fg   = tid >> 8;
    int q = lane >> 4, t = lane & 15;
    const float* src = x + (size_t)(mt * 16 + t) * IN_F + fg * 32 + q * 8;
    u16x8 o;
#pragma unroll
    for (int j = 0; j < 8; ++j) o[j] = f2bf_rne(src[j]);
    *reinterpret_cast<u16x8*>(xs + (size_t)tid * 8) = o;
}

// Repack (R8-verified layout): rep dword ((G*64+g)*64 + q*16 + t)*4 + i holds
// payload bytes of wp[(G*16+t)*KPI + 64g + 16i + 4q + 0..3].
__global__ __launch_bounds__(256) void qlin_repack(const int* __restrict__ wp,
                                                   unsigned* __restrict__ rep) {
    __shared__ unsigned lds[2048];                  // 8 KB
    const int G   = blockIdx.x >> 3;                // 0..895
    const int g8  = blockIdx.x & 7;
    const int tid = threadIdx.x;
    const int r = tid >> 4, T = tid & 15;
    const int q = T & 3, i = T >> 2;
    const int* src = wp + (size_t)(G * 16 + r) * KPI + T * 4;
#pragma unroll
    for (int j = 0; j < 8; ++j) {
        const int g = g8 * 8 + j;
        int4 v = *reinterpret_cast<const int4*>(src + 64 * g);
        unsigned d = (unsigned)(v.x & 255) | ((unsigned)(v.y & 255) << 8)
                   | ((unsigned)(v.z & 255) << 16) | ((unsigned)(v.w & 255) << 24);
        lds[j * 256 + q * 64 + r * 4 + i] = d;
    }
    __syncthreads();
    unsigned* dst = rep + ((size_t)G * 64 + g8 * 8) * 256;
#pragma unroll
    for (int s = 0; s < 2; ++s)
        *reinterpret_cast<uint4*>(dst + s * 1024 + tid * 4) =
            *reinterpret_cast<const uint4*>(&lds[s * 1024 + tid * 4]);
}

// payload byte (lo nibble = even k, hi nibble = odd k) -> two bf16 bit-patterns.
__device__ __forceinline__ int unpack2_bf16(int v) {
    int q0 = ((int)((unsigned)v << 28)) >> 28;
    int q1 = ((int)((unsigned)v << 24)) >> 28;
    unsigned u0 = __builtin_bit_cast(unsigned, (float)q0);
    unsigned u1 = __builtin_bit_cast(unsigned, (float)q1);
    return (int)((u0 >> 16) | (u1 & 0xFFFF0000u));
}

__device__ __forceinline__ bf16x8 unpack_frag(unsigned d) {
    int4 pk;
    pk.x = unpack2_bf16((int)(d));
    pk.y = unpack2_bf16((int)(d >> 8));
    pk.z = unpack2_bf16((int)(d >> 16));
    pk.w = unpack2_bf16((int)(d >> 24));
    return __builtin_bit_cast(bf16x8, pk);
}

// GEMM v3 (R9) + NREP instrumentation: K-loop executed NREP times (acc = NREP x
// true sum; epilogue scales by 1/NREP — exact). Purpose: gemm dispatch dur
// becomes ~NREP x real -> surfaces in top-5 with full counters; dur delta vs
// R9 = (NREP-1) x gemm_dur. Everything else identical to R9.
__global__ __launch_bounds__(256, 2) void qlin_gemm(const unsigned short* __restrict__ xs,
                                                    const unsigned* __restrict__ rep,
                                                    float* __restrict__ part) {
    __shared__ float red[4 * 128 * 32];             // 64 KB
    const int tid  = threadIdx.x;
    const int wave = tid >> 6;
    const int lane = tid & 63;
    const int t = lane & 15;
    const int q = lane >> 4;

    const int nb   = blockIdx.x % NBLK;
    const int kblk = blockIdx.x / NBLK;
    const int g0   = kblk * 16 + wave * 4;          // wave's first 128-k group

    const unsigned* wbase = rep + ((size_t)(nb * 8 * 64 + g0) * 64 + lane) * 4;

    f32x4 acc[8][4] = {};   // [ng][mt]

#pragma unroll 1
    for (int rpt = 0; rpt < NREP; ++rpt) {
#pragma unroll
        for (int sub = 0; sub < 4; ++sub) {
            const int g = g0 + sub;
            bf16x8 a[4][4];                         // [i][mt]
#pragma unroll
            for (int i = 0; i < 4; ++i)
#pragma unroll
                for (int mt = 0; mt < 4; ++mt)
                    a[i][mt] = *reinterpret_cast<const bf16x8*>(
                        xs + ((size_t)((g * 4 + i) * 4 + mt) * 64 + lane) * 8);
#pragma unroll
            for (int ng = 0; ng < 8; ++ng) {
                uint4 wd = *reinterpret_cast<const uint4*>(
                    wbase + (size_t)ng * 16384 + sub * 256);
                const unsigned* d = reinterpret_cast<const unsigned*>(&wd);
#pragma unroll
                for (int i = 0; i < 4; ++i) {
                    bf16x8 b = unpack_frag(d[i]);
#pragma unroll
                    for (int mt = 0; mt < 4; ++mt)
                        acc[ng][mt] = __builtin_amdgcn_mfma_f32_16x16x32_bf16(
                            a[i][mt], b, acc[ng][mt], 0, 0, 0);
                }
            }
        }
    }

    // ---- epilogue: two m-halves through 64-KB LDS; scale by 1/NREP ----
    const float inv = 1.0f / (float)NREP;
#pragma unroll
    for (int h = 0; h < 2; ++h) {
        if (h) __syncthreads();
#pragma unroll
        for (int ng = 0; ng < 8; ++ng)
#pragma unroll
            for (int mi = 0; mi < 2; ++mi)
#pragma unroll
                for (int r = 0; r < 4; ++r)
                    red[wave * 4096 + (ng * 16 + t) * 32 + mi * 16 + q * 4 + r] =
                        acc[ng][h * 2 + mi][r];
        __syncthreads();

        const int ml = tid >> 3;
        const int nq = tid & 7;
        float* p = part + (size_t)kblk * PSTR
                 + (size_t)(h * 32 + ml) * OUT_F + nb * 128;
#pragma unroll
        for (int j = 0; j < 4; ++j) {
            const int nf = nq + j * 8;
            float4 v;
#pragma unroll
            for (int e = 0; e < 4; ++e) {
                const int nl = nf * 4 + e;
                v[e] = inv * (red[0 * 4096 + nl * 32 + ml] + red[1 * 4096 + nl * 32 + ml]
                            + red[2 * 4096 + nl * 32 + ml] + red[3 * 4096 + nl * 32 + ml]);
            }
            *reinterpret_cast<float4*>(p + nf * 4) = v;
        }
    }
}

// out = (sum of 4 raw partials) * scale[n] + bias[n]. 229376 float4 threads.
__global__ __launch_bounds__(256) void qlin_reduce(const float* __restrict__ part,
                                                   const float* __restrict__ scales,
                                                   const float* __restrict__ bias,
                                                   float* __restrict__ out) {
    int g  = blockIdx.x * 256 + threadIdx.x;        // 0..229375
    int n4 = g % (OUT_F / 4);
    float4 s4 = reinterpret_cast<const float4*>(scales)[n4];
    float4 b4 = reinterpret_cast<const float4*>(bias)[n4];
    float4 a = {0.f, 0.f, 0.f, 0.f};
#pragma unroll
    for (int s = 0; s < KSPLIT; ++s) {
        float4 v = reinterpret_cast<const float4*>(part)[(size_t)s * (PSTR / 4) + g];
        a.x += v.x; a.y += v.y; a.z += v.z; a.w += v.w;
    }
    float4 o;
    o.x = a.x * s4.x + b4.x;
    o.y = a.y * s4.y + b4.y;
    o.z = a.z * s4.z + b4.z;
    o.w = a.w * s4.w + b4.w;
    reinterpret_cast<float4*>(out)[g] = o;
}

extern "C" void kernel_launch(void* const* d_in, const int* in_sizes, int n_in,
                              void* d_out, int out_size, void* d_ws, size_t ws_size,
                              hipStream_t stream) {
    const float* x    = (const float*)d_in[0];
    const int*   wp   = (const int*)d_in[1];
    const float* sc   = (const float*)d_in[2];
    const float* bias = (const float*)d_in[3];
    float* out = (float*)d_out;

    unsigned short* xs   = (unsigned short*)d_ws;                    // 1 MiB
    unsigned*       rp   = (unsigned*)((char*)d_ws + (1 << 20));     // 56 MiB
    float*          part = (float*)((char*)d_ws + (64u << 20));      // 4 x 3.5 MiB

    qlin_prep<<<256, 256, 0, stream>>>(x, xs);
    qlin_repack<<<896 * 8, 256, 0, stream>>>(wp, rp);
    qlin_gemm<<<NBLK * KSPLIT, 256, 0, stream>>>(xs, rp, part);
    qlin_reduce<<<(M_TOK * OUT_F) / 4 / 256, 256, 0, stream>>>(part, sc, bias, out);
}